// Round 4
// baseline (214.984 us; speedup 1.0000x reference)
//
#include <hip/hip_runtime.h>

#define B 32
#define M 32
#define H 128
#define EPS 1e-6f
#define TSCALE 2.8853900817779268f   // 2*log2(e)

// ---------------- workspace layout (floats) ----------------
// metric @ 0      : 32768
// mj     @ 32768  : 262144   mj[b][j][d] = metric[b,j,:] @ Wr1[64:96]
// S      @ 294912 : 8192
// bc1s   @ 303104 : 128      bc1 * 2log2(e)
// Kc     @ 303232 : 1        sum(Wc2) + bc2
// cnt    @ 303236 : 32 ints  per-b completion counters

#define FMA4(P, s, W) \
    P.x = fmaf((s), (W).x, P.x); P.y = fmaf((s), (W).y, P.y); \
    P.z = fmaf((s), (W).z, P.z); P.w = fmaf((s), (W).w, P.w);

#define RL(v, ln) __int_as_float(__builtin_amdgcn_readlane(__float_as_int(v), (ln)))

// Kernel 1: metric + mj + zero S/cnt + scaled christoffel constants.
__global__ __launch_bounds__(256) void k_prep(
    const float* __restrict__ points, const float* __restrict__ Wm1,
    const float* __restrict__ bm1, const float* __restrict__ Wm2,
    const float* __restrict__ bm2, const float* __restrict__ Wr1,
    const float* __restrict__ bc1, const float* __restrict__ Wc2,
    const float* __restrict__ bc2,
    float* __restrict__ metric, float* __restrict__ mj,
    float* __restrict__ S, float* __restrict__ bc1s, float* __restrict__ Kc,
    int* __restrict__ cnt)
{
    const int b = blockIdx.x, t = threadIdx.x;
    __shared__ float p[M];
    __shared__ float h[H];
    __shared__ float comps[M * M];
    __shared__ float msym[M * M];
    if (t < M) p[t] = points[b * M + t];
    __syncthreads();
    if (t < H) {
        float acc = bm1[t];
        #pragma unroll
        for (int m = 0; m < M; ++m) acc = fmaf(p[m], Wm1[m * H + t], acc);
        h[t] = fmaxf(acc, 0.f);
    }
    __syncthreads();
    #pragma unroll
    for (int r = 0; r < 4; ++r) {
        const int d = t + 256 * r;
        float acc = bm2[d];
        for (int u = 0; u < H; ++u) acc = fmaf(h[u], Wm2[u * (M * M) + d], acc);
        comps[d] = acc;
    }
    __syncthreads();
    #pragma unroll
    for (int r = 0; r < 4; ++r) {
        const int d = t + 256 * r;
        const int ii = d >> 5, jj = d & 31;
        float v = 0.5f * (comps[ii * M + jj] + comps[jj * M + ii]) + (ii == jj ? EPS : 0.f);
        metric[b * M * M + d] = v;
        msym[d] = v;
    }
    S[b * 256 + t] = 0.f;
    if (t == 0) cnt[b] = 0;
    __syncthreads();
    // mj[b][x][t]: weight column cached in registers, reused across all x
    float wreg[M];
    #pragma unroll
    for (int m = 0; m < M; ++m) wreg[m] = Wr1[(64 + m) * 256 + t];
    const float4* msym4 = (const float4*)msym;
    for (int x = 0; x < M; ++x) {
        float acc = 0.f;
        #pragma unroll
        for (int mq = 0; mq < 8; ++mq) {
            float4 mv = msym4[x * 8 + mq];
            acc = fmaf(mv.x, wreg[4 * mq + 0], acc);
            acc = fmaf(mv.y, wreg[4 * mq + 1], acc);
            acc = fmaf(mv.z, wreg[4 * mq + 2], acc);
            acc = fmaf(mv.w, wreg[4 * mq + 3], acc);
        }
        mj[(b * M + x) * 256 + t] = acc;
    }
    if (b == 0) {
        if (t < H) bc1s[t] = bc1[t] * TSCALE;
        if (t == 0) {
            float s = bc2[0];
            for (int u = 0; u < H; ++u) s += Wc2[u];
            Kc[0] = s;
        }
    }
}

// Kernel 2: per block (b,i): christoffel MLP + ricci layer-1 + reduce into
// S[b]; the 32nd block per b runs the finish epilogue (ricci@Wr2, flow,
// hamiltonian, output). 512 threads = 8 waves; wave w owns
// j in {2w, 2w+1, 16+2w, 16+2w+1}. LDS < 40 KB -> 4 blocks/CU, zero tail.
__global__ __launch_bounds__(512, 8) void k_main(
    const float* __restrict__ points, const float* __restrict__ metric,
    const float* __restrict__ mj, const float* __restrict__ Wc1,
    const float* __restrict__ Wc2, const float* __restrict__ bc1s,
    const float* __restrict__ Kc, const float* __restrict__ Wr1,
    const float* __restrict__ br1, float* __restrict__ S,
    int* __restrict__ cnt,
    const float* __restrict__ Wr2, const float* __restrict__ br2,
    const float* __restrict__ Wf1, const float* __restrict__ bf1,
    const float* __restrict__ Wf2, const float* __restrict__ bf2,
    const float* __restrict__ Wh1, const float* __restrict__ bh1,
    const float* __restrict__ Wh2, const float* __restrict__ bh2,
    float* __restrict__ out)
{
    const int blk = blockIdx.x;
    const int b = blk >> 5, i = blk & 31;
    const int t = threadIdx.x;

    __shared__ float wr1c[M * 256];   // Wr1[96:128] — 32 KB (reused as scratch in epilogue)
    __shared__ float mlds[M * M];     // 4 KB
    __shared__ float bmi[256];
    __shared__ float Slds[256];
    __shared__ int finflag;

    {
        const float4* src = (const float4*)(Wr1 + 96 * 256);
        float4* dst = (float4*)wr1c;
        #pragma unroll
        for (int r = 0; r < 4; ++r) dst[t + 512 * r] = src[t + 512 * r];
    }
    mlds[t] = metric[b * 1024 + t];
    mlds[t + 512] = metric[b * 1024 + t + 512];
    if (t < 256) Slds[t] = 0.f;
    __syncthreads();

    if (t < 256) {
        float acc = br1[t];
        #pragma unroll
        for (int m = 0; m < M; ++m) acc = fmaf(points[b * M + m], Wr1[m * 256 + t], acc);
        #pragma unroll
        for (int m = 0; m < M; ++m) acc = fmaf(mlds[i * M + m], Wr1[(32 + m) * 256 + t], acc);
        bmi[t] = acc;
    }

    const int w = t >> 6, l = t & 63;
    const int ph = l >> 5, k = l & 31;
    const int j0 = 2 * w + ph, j1 = 16 + 2 * w + ph;
    const float gki  = mlds[i * M + k] * TSCALE;   // metric symmetric
    const float gij0 = mlds[i * M + j0] * TSCALE;
    const float gij1 = mlds[i * M + j1] * TSCALE;
    const float gjk0 = mlds[j0 * M + k] * TSCALE;
    const float gjk1 = mlds[j1 * M + k] * TSCALE;

    // --- christoffel: both j's in one pass, shared gki term ---
    float acc_a = 0.f, acc_b = 0.f;
    #pragma unroll 8
    for (int u = 0; u < H; ++u) {
        float tc = fmaf(gki, Wc1[2 * H + u], bc1s[u]);
        float pa = fmaf(gij0, Wc1[u], fmaf(gjk0, Wc1[H + u], tc));
        float pb = fmaf(gij1, Wc1[u], fmaf(gjk1, Wc1[H + u], tc));
        acc_a = fmaf(__builtin_amdgcn_rcpf(__builtin_amdgcn_exp2f(pa) + 1.f), Wc2[u], acc_a);
        acc_b = fmaf(__builtin_amdgcn_rcpf(__builtin_amdgcn_exp2f(pb) + 1.f), Wc2[u], acc_b);
    }
    const float KcV = Kc[0];
    const float ca = fmaf(-2.f, acc_a, KcV);   // chris for (j0, k), lanes 0-31: j=2w, 32-63: j=2w+1
    const float cb = fmaf(-2.f, acc_b, KcV);   // chris for (j1, k)
    __syncthreads();   // bmi ready

    // --- ricci layer-1: lane l owns dims 4l..4l+3 for the wave's 4 j's ---
    const float4* mj4 = (const float4*)(mj + b * M * 256);
    const float4* wr1c4 = (const float4*)wr1c;
    float4 bmiv = ((const float4*)bmi)[l];
    const int jb = w * 2;
    float4 p00 = mj4[(jb + 0) * 64 + l];
    float4 p01 = mj4[(jb + 1) * 64 + l];
    float4 p10 = mj4[(jb + 16) * 64 + l];
    float4 p11 = mj4[(jb + 17) * 64 + l];
    p00.x += bmiv.x; p00.y += bmiv.y; p00.z += bmiv.z; p00.w += bmiv.w;
    p01.x += bmiv.x; p01.y += bmiv.y; p01.z += bmiv.z; p01.w += bmiv.w;
    p10.x += bmiv.x; p10.y += bmiv.y; p10.z += bmiv.z; p10.w += bmiv.w;
    p11.x += bmiv.x; p11.y += bmiv.y; p11.z += bmiv.z; p11.w += bmiv.w;

    #define STEP(W, kk) { \
        float s0 = RL(ca, (kk));      float s1 = RL(ca, 32 + (kk)); \
        float s2 = RL(cb, (kk));      float s3 = RL(cb, 32 + (kk)); \
        FMA4(p00, s0, W); FMA4(p01, s1, W); FMA4(p10, s2, W); FMA4(p11, s3, W); }

    #pragma unroll
    for (int kc = 0; kc < 4; ++kc) {
        const int kb = kc * 8;
        float4 w0 = wr1c4[(kb + 0) * 64 + l];
        float4 w1 = wr1c4[(kb + 1) * 64 + l];
        float4 w2 = wr1c4[(kb + 2) * 64 + l];
        float4 w3 = wr1c4[(kb + 3) * 64 + l];
        float4 w4 = wr1c4[(kb + 4) * 64 + l];
        float4 w5 = wr1c4[(kb + 5) * 64 + l];
        float4 w6 = wr1c4[(kb + 6) * 64 + l];
        float4 w7 = wr1c4[(kb + 7) * 64 + l];
        STEP(w0, kb + 0) STEP(w1, kb + 1) STEP(w2, kb + 2) STEP(w3, kb + 3)
        STEP(w4, kb + 4) STEP(w5, kb + 5) STEP(w6, kb + 6) STEP(w7, kb + 7)
    }
    #undef STEP

    float r0 = fmaxf(p00.x,0.f)+fmaxf(p01.x,0.f)+fmaxf(p10.x,0.f)+fmaxf(p11.x,0.f);
    float r1 = fmaxf(p00.y,0.f)+fmaxf(p01.y,0.f)+fmaxf(p10.y,0.f)+fmaxf(p11.y,0.f);
    float r2 = fmaxf(p00.z,0.f)+fmaxf(p01.z,0.f)+fmaxf(p10.z,0.f)+fmaxf(p11.z,0.f);
    float r3 = fmaxf(p00.w,0.f)+fmaxf(p01.w,0.f)+fmaxf(p10.w,0.f)+fmaxf(p11.w,0.f);
    atomicAdd(&Slds[4*l + 0], r0);
    atomicAdd(&Slds[4*l + 1], r1);
    atomicAdd(&Slds[4*l + 2], r2);
    atomicAdd(&Slds[4*l + 3], r3);
    __syncthreads();
    if (t < 256) atomicAdd(&S[b * 256 + t], Slds[t]);
    __threadfence();
    __syncthreads();
    if (t == 0) {
        int old = atomicAdd(&cnt[b], 1);
        finflag = (old == 31);
    }
    __syncthreads();
    if (!finflag) return;

    // ================= finish epilogue (one block per b) =================
    __threadfence();
    float* fs   = wr1c;          // 256
    float* P    = wr1c + 256;    // 1024
    float* ric  = wr1c + 1280;   // 1024
    float* pl   = wr1c + 2304;   // 32
    float* fin  = wr1c + 2336;   // 64
    float* hf   = wr1c + 2400;   // 128
    float* npos = wr1c + 2528;   // 32
    float* hh   = wr1c + 2560;   // 128

    if (t < 256) fs[t] = atomicAdd(&S[b * 256 + t], 0.f) * (1.f / 1024.f);
    if (t < M) pl[t] = points[b * M + t];
    __syncthreads();
    #pragma unroll
    for (int r = 0; r < 2; ++r) {
        const int d = t + 512 * r;
        float acc = br2[d];
        for (int u = 0; u < 256; ++u) acc = fmaf(fs[u], Wr2[u * (M * M) + d], acc);
        P[d] = acc;
    }
    __syncthreads();
    #pragma unroll
    for (int r = 0; r < 2; ++r) {
        const int d = t + 512 * r;
        const int ii = d >> 5, jj = d & 31;
        ric[d] = 0.5f * (P[d] + P[jj * M + ii]);
    }
    __syncthreads();
    if (t < M) {
        float acc = 0.f;
        #pragma unroll
        for (int jj = 0; jj < M; ++jj) acc = fmaf(ric[t * M + jj], pl[jj], acc);
        fin[t] = pl[t];
        fin[M + t] = acc;
    }
    __syncthreads();
    if (t < H) {
        float acc = bf1[t];
        #pragma unroll
        for (int m = 0; m < 2 * M; ++m) acc = fmaf(fin[m], Wf1[m * H + t], acc);
        hf[t] = fmaxf(acc, 0.f);
    }
    __syncthreads();
    if (t < M) {
        float acc = bf2[t];
        #pragma unroll
        for (int u = 0; u < H; ++u) acc = fmaf(hf[u], Wf2[u * M + t], acc);
        npos[t] = pl[t] + acc;
    }
    __syncthreads();
    if (t < H) {
        float acc = bh1[t];
        #pragma unroll
        for (int m = 0; m < M; ++m) acc = fmaf(npos[m], Wh1[m * H + t], acc);
        hh[t] = tanhf(acc);
    }
    __syncthreads();
    if (t < 2 * M) {
        float acc = bh2[t];
        #pragma unroll
        for (int u = 0; u < H; ++u) acc = fmaf(hh[u], Wh2[u * (2 * M) + t], acc);
        out[b * (2 * M) + t] = acc;
    }
}

extern "C" void kernel_launch(void* const* d_in, const int* in_sizes, int n_in,
                              void* d_out, int out_size, void* d_ws, size_t ws_size,
                              hipStream_t stream)
{
    const float* points = (const float*)d_in[0];
    const float* Wm1 = (const float*)d_in[1];
    const float* bm1 = (const float*)d_in[2];
    const float* Wm2 = (const float*)d_in[3];
    const float* bm2 = (const float*)d_in[4];
    const float* Wc1 = (const float*)d_in[5];
    const float* bc1 = (const float*)d_in[6];
    const float* Wc2 = (const float*)d_in[7];
    const float* bc2 = (const float*)d_in[8];
    const float* Wr1 = (const float*)d_in[9];
    const float* br1 = (const float*)d_in[10];
    const float* Wr2 = (const float*)d_in[11];
    const float* br2 = (const float*)d_in[12];
    const float* Wf1 = (const float*)d_in[13];
    const float* bf1 = (const float*)d_in[14];
    const float* Wf2 = (const float*)d_in[15];
    const float* bf2 = (const float*)d_in[16];
    const float* Wh1 = (const float*)d_in[17];
    const float* bh1 = (const float*)d_in[18];
    const float* Wh2 = (const float*)d_in[19];
    const float* bh2 = (const float*)d_in[20];
    float* out = (float*)d_out;

    float* ws     = (float*)d_ws;
    float* metric = ws;                    // 32768
    float* mj     = ws + 32768;            // 262144
    float* S      = ws + 294912;           // 8192
    float* bc1s   = ws + 303104;           // 128
    float* Kc     = ws + 303232;           // 1
    int*   cnt    = (int*)(ws + 303236);   // 32 ints

    k_prep<<<B, 256, 0, stream>>>(points, Wm1, bm1, Wm2, bm2, Wr1, bc1, Wc2, bc2,
                                  metric, mj, S, bc1s, Kc, cnt);
    k_main<<<B * M, 512, 0, stream>>>(points, metric, mj, Wc1, Wc2, bc1s, Kc,
                                      Wr1, br1, S, cnt,
                                      Wr2, br2, Wf1, bf1, Wf2, bf2,
                                      Wh1, bh1, Wh2, bh2, out);
}

// Round 5
// 88.733 us; speedup vs baseline: 2.4228x; 2.4228x over previous
//
#include <hip/hip_runtime.h>

#define B 32
#define M 32
#define H 128
#define EPS 1e-6f
#define TSCALE 2.8853900817779268f   // 2*log2(e)

// ---------------- workspace layout (floats) ----------------
// metric @ 0      : 32768
// mj     @ 32768  : 262144   mj[b][j][d] = metric[b,j,:] @ Wr1[64:96]
// S      @ 294912 : 8192
// bc1s   @ 303104 : 128      bc1 * 2log2(e)
// Kc     @ 303232 : 1        sum(Wc2) + bc2
// cnt    @ 303236 : 32 ints  per-b completion counters

#define FMA4(P, s, W) \
    P.x = fmaf((s), (W).x, P.x); P.y = fmaf((s), (W).y, P.y); \
    P.z = fmaf((s), (W).z, P.z); P.w = fmaf((s), (W).w, P.w);

// Kernel 1: metric + mj + zero S/cnt + scaled christoffel constants.
__global__ __launch_bounds__(256) void k_prep(
    const float* __restrict__ points, const float* __restrict__ Wm1,
    const float* __restrict__ bm1, const float* __restrict__ Wm2,
    const float* __restrict__ bm2, const float* __restrict__ Wr1,
    const float* __restrict__ bc1, const float* __restrict__ Wc2,
    const float* __restrict__ bc2,
    float* __restrict__ metric, float* __restrict__ mj,
    float* __restrict__ S, float* __restrict__ bc1s, float* __restrict__ Kc,
    int* __restrict__ cnt)
{
    const int b = blockIdx.x, t = threadIdx.x;
    __shared__ float p[M];
    __shared__ float h[H];
    __shared__ float comps[M * M];
    __shared__ float msym[M * M];
    if (t < M) p[t] = points[b * M + t];
    __syncthreads();
    if (t < H) {
        float acc = bm1[t];
        #pragma unroll
        for (int m = 0; m < M; ++m) acc = fmaf(p[m], Wm1[m * H + t], acc);
        h[t] = fmaxf(acc, 0.f);
    }
    __syncthreads();
    #pragma unroll
    for (int r = 0; r < 4; ++r) {
        const int d = t + 256 * r;
        float acc = bm2[d];
        for (int u = 0; u < H; ++u) acc = fmaf(h[u], Wm2[u * (M * M) + d], acc);
        comps[d] = acc;
    }
    __syncthreads();
    #pragma unroll
    for (int r = 0; r < 4; ++r) {
        const int d = t + 256 * r;
        const int ii = d >> 5, jj = d & 31;
        float v = 0.5f * (comps[ii * M + jj] + comps[jj * M + ii]) + (ii == jj ? EPS : 0.f);
        metric[b * M * M + d] = v;
        msym[d] = v;
    }
    S[b * 256 + t] = 0.f;
    if (t == 0) cnt[b] = 0;
    __syncthreads();
    // mj[b][x][t]: weight column cached in registers, reused across all x
    float wreg[M];
    #pragma unroll
    for (int m = 0; m < M; ++m) wreg[m] = Wr1[(64 + m) * 256 + t];
    const float4* msym4 = (const float4*)msym;
    for (int x = 0; x < M; ++x) {
        float acc = 0.f;
        #pragma unroll
        for (int mq = 0; mq < 8; ++mq) {
            float4 mv = msym4[x * 8 + mq];
            acc = fmaf(mv.x, wreg[4 * mq + 0], acc);
            acc = fmaf(mv.y, wreg[4 * mq + 1], acc);
            acc = fmaf(mv.z, wreg[4 * mq + 2], acc);
            acc = fmaf(mv.w, wreg[4 * mq + 3], acc);
        }
        mj[(b * M + x) * 256 + t] = acc;
    }
    if (b == 0) {
        if (t < H) bc1s[t] = bc1[t] * TSCALE;
        if (t == 0) {
            float s = bc2[0];
            for (int u = 0; u < H; ++u) s += Wc2[u];
            Kc[0] = s;
        }
    }
}

// Kernel 2: per block (b,i): christoffel MLP + ricci layer-1 + reduce into
// S[b]; the 32nd finishing block per b runs the epilogue. 512 threads =
// 8 waves; wave w owns j in {2w, 2w+1, 16+2w, 16+2w+1}.
// LDS ~38.9 KB -> 4 blocks/CU. launch_bounds(512,6): (512,8) forced a
// 64-VGPR cap and spilled the float4 accumulators (round-4 regression).
__global__ __launch_bounds__(512, 6) void k_main(
    const float* __restrict__ points, const float* __restrict__ metric,
    const float* __restrict__ mj, const float* __restrict__ Wc1,
    const float* __restrict__ Wc2, const float* __restrict__ bc1s,
    const float* __restrict__ Kc, const float* __restrict__ Wr1,
    const float* __restrict__ br1, float* __restrict__ S,
    int* __restrict__ cnt,
    const float* __restrict__ Wr2, const float* __restrict__ br2,
    const float* __restrict__ Wf1, const float* __restrict__ bf1,
    const float* __restrict__ Wf2, const float* __restrict__ bf2,
    const float* __restrict__ Wh1, const float* __restrict__ bh1,
    const float* __restrict__ Wh2, const float* __restrict__ bh2,
    float* __restrict__ out)
{
    const int blk = blockIdx.x;
    const int b = blk >> 5, i = blk & 31;
    const int t = threadIdx.x;

    __shared__ float wr1c[M * 256];   // Wr1[96:128] — 32 KB (epilogue scratch later)
    __shared__ float mc[M * M];       // metric[b] first, chris scratch after
    __shared__ float bmi[256];
    __shared__ float Slds[256];
    __shared__ int finflag;

    {
        const float4* src = (const float4*)(Wr1 + 96 * 256);
        float4* dst = (float4*)wr1c;
        #pragma unroll
        for (int r = 0; r < 4; ++r) dst[t + 512 * r] = src[t + 512 * r];
    }
    mc[t] = metric[b * 1024 + t];
    mc[t + 512] = metric[b * 1024 + t + 512];
    if (t < 256) Slds[t] = 0.f;
    __syncthreads();

    if (t < 256) {
        float acc = br1[t];
        #pragma unroll
        for (int m = 0; m < M; ++m) acc = fmaf(points[b * M + m], Wr1[m * 256 + t], acc);
        #pragma unroll
        for (int m = 0; m < M; ++m) acc = fmaf(mc[i * M + m], Wr1[(32 + m) * 256 + t], acc);
        bmi[t] = acc;
    }

    const int w = t >> 6, l = t & 63;
    const int ph = l >> 5, k = l & 31;
    const int j0 = 2 * w + ph, j1 = 16 + 2 * w + ph;
    const float gki  = mc[i * M + k] * TSCALE;   // metric symmetric
    const float gij0 = mc[i * M + j0] * TSCALE;
    const float gij1 = mc[i * M + j1] * TSCALE;
    const float gjk0 = mc[j0 * M + k] * TSCALE;
    const float gjk1 = mc[j1 * M + k] * TSCALE;
    __syncthreads();   // all mc(metric) reads done; bmi written

    // --- christoffel: both j's in one pass, shared gki term ---
    float acc_a = 0.f, acc_b = 0.f;
    #pragma unroll 8
    for (int u = 0; u < H; ++u) {
        float tc = fmaf(gki, Wc1[2 * H + u], bc1s[u]);
        float pa = fmaf(gij0, Wc1[u], fmaf(gjk0, Wc1[H + u], tc));
        float pb = fmaf(gij1, Wc1[u], fmaf(gjk1, Wc1[H + u], tc));
        acc_a = fmaf(__builtin_amdgcn_rcpf(__builtin_amdgcn_exp2f(pa) + 1.f), Wc2[u], acc_a);
        acc_b = fmaf(__builtin_amdgcn_rcpf(__builtin_amdgcn_exp2f(pb) + 1.f), Wc2[u], acc_b);
    }
    const float KcV = Kc[0];
    // chris scratch overlays mc: [w*128 + 0..63] = j0 group, [.. +64..127] = j1
    mc[w * 128 + l]      = fmaf(-2.f, acc_a, KcV);
    mc[w * 128 + 64 + l] = fmaf(-2.f, acc_b, KcV);
    __syncthreads();

    // --- ricci layer-1: lane l owns dims 4l..4l+3 for the wave's 4 j's ---
    const float4* mj4 = (const float4*)(mj + b * M * 256);
    const float4* wr1c4 = (const float4*)wr1c;
    const float* chw = mc + w * 128;
    float4 bmiv = ((const float4*)bmi)[l];
    const int jb = w * 2;
    float4 p00 = mj4[(jb + 0) * 64 + l];
    float4 p01 = mj4[(jb + 1) * 64 + l];
    float4 p10 = mj4[(jb + 16) * 64 + l];
    float4 p11 = mj4[(jb + 17) * 64 + l];
    p00.x += bmiv.x; p00.y += bmiv.y; p00.z += bmiv.z; p00.w += bmiv.w;
    p01.x += bmiv.x; p01.y += bmiv.y; p01.z += bmiv.z; p01.w += bmiv.w;
    p10.x += bmiv.x; p10.y += bmiv.y; p10.z += bmiv.z; p10.w += bmiv.w;
    p11.x += bmiv.x; p11.y += bmiv.y; p11.z += bmiv.z; p11.w += bmiv.w;

    #define STEP(W, kk) { \
        float s0 = chw[(kk)];      float s1 = chw[32 + (kk)]; \
        float s2 = chw[64 + (kk)]; float s3 = chw[96 + (kk)]; \
        FMA4(p00, s0, W); FMA4(p01, s1, W); FMA4(p10, s2, W); FMA4(p11, s3, W); }

    #pragma unroll
    for (int kc = 0; kc < 4; ++kc) {
        const int kb = kc * 8;
        float4 w0 = wr1c4[(kb + 0) * 64 + l];
        float4 w1 = wr1c4[(kb + 1) * 64 + l];
        float4 w2 = wr1c4[(kb + 2) * 64 + l];
        float4 w3 = wr1c4[(kb + 3) * 64 + l];
        float4 w4 = wr1c4[(kb + 4) * 64 + l];
        float4 w5 = wr1c4[(kb + 5) * 64 + l];
        float4 w6 = wr1c4[(kb + 6) * 64 + l];
        float4 w7 = wr1c4[(kb + 7) * 64 + l];
        STEP(w0, kb + 0) STEP(w1, kb + 1) STEP(w2, kb + 2) STEP(w3, kb + 3)
        STEP(w4, kb + 4) STEP(w5, kb + 5) STEP(w6, kb + 6) STEP(w7, kb + 7)
    }
    #undef STEP

    float r0 = fmaxf(p00.x,0.f)+fmaxf(p01.x,0.f)+fmaxf(p10.x,0.f)+fmaxf(p11.x,0.f);
    float r1 = fmaxf(p00.y,0.f)+fmaxf(p01.y,0.f)+fmaxf(p10.y,0.f)+fmaxf(p11.y,0.f);
    float r2 = fmaxf(p00.z,0.f)+fmaxf(p01.z,0.f)+fmaxf(p10.z,0.f)+fmaxf(p11.z,0.f);
    float r3 = fmaxf(p00.w,0.f)+fmaxf(p01.w,0.f)+fmaxf(p10.w,0.f)+fmaxf(p11.w,0.f);
    atomicAdd(&Slds[4*l + 0], r0);
    atomicAdd(&Slds[4*l + 1], r1);
    atomicAdd(&Slds[4*l + 2], r2);
    atomicAdd(&Slds[4*l + 3], r3);
    __syncthreads();
    if (t < 256) atomicAdd(&S[b * 256 + t], Slds[t]);
    // S and cnt are only ever touched via device-scope atomics (coherent at
    // their execution point) — only completion ordering is needed, which the
    // vmcnt(0) drain in __syncthreads() provides. No __threadfence.
    asm volatile("s_waitcnt vmcnt(0)" ::: "memory");
    __syncthreads();
    if (t == 0) {
        int old = atomicAdd(&cnt[b], 1);
        finflag = (old == 31);
    }
    __syncthreads();
    if (!finflag) return;

    // ================= finish epilogue (one block per b) =================
    float* fs   = wr1c;          // 256
    float* P    = wr1c + 256;    // 1024
    float* ric  = wr1c + 1280;   // 1024
    float* pl   = wr1c + 2304;   // 32
    float* fin  = wr1c + 2336;   // 64
    float* hf   = wr1c + 2400;   // 128
    float* npos = wr1c + 2528;   // 32
    float* hh   = wr1c + 2560;   // 128

    if (t < 256) fs[t] = atomicAdd(&S[b * 256 + t], 0.f) * (1.f / 1024.f);
    if (t < M) pl[t] = points[b * M + t];
    __syncthreads();
    #pragma unroll
    for (int r = 0; r < 2; ++r) {
        const int d = t + 512 * r;
        float acc = br2[d];
        for (int u = 0; u < 256; ++u) acc = fmaf(fs[u], Wr2[u * (M * M) + d], acc);
        P[d] = acc;
    }
    __syncthreads();
    #pragma unroll
    for (int r = 0; r < 2; ++r) {
        const int d = t + 512 * r;
        const int ii = d >> 5, jj = d & 31;
        ric[d] = 0.5f * (P[d] + P[jj * M + ii]);
    }
    __syncthreads();
    if (t < M) {
        float acc = 0.f;
        #pragma unroll
        for (int jj = 0; jj < M; ++jj) acc = fmaf(ric[t * M + jj], pl[jj], acc);
        fin[t] = pl[t];
        fin[M + t] = acc;
    }
    __syncthreads();
    if (t < H) {
        float acc = bf1[t];
        #pragma unroll
        for (int m = 0; m < 2 * M; ++m) acc = fmaf(fin[m], Wf1[m * H + t], acc);
        hf[t] = fmaxf(acc, 0.f);
    }
    __syncthreads();
    if (t < M) {
        float acc = bf2[t];
        #pragma unroll
        for (int u = 0; u < H; ++u) acc = fmaf(hf[u], Wf2[u * M + t], acc);
        npos[t] = pl[t] + acc;
    }
    __syncthreads();
    if (t < H) {
        float acc = bh1[t];
        #pragma unroll
        for (int m = 0; m < M; ++m) acc = fmaf(npos[m], Wh1[m * H + t], acc);
        hh[t] = tanhf(acc);
    }
    __syncthreads();
    if (t < 2 * M) {
        float acc = bh2[t];
        #pragma unroll
        for (int u = 0; u < H; ++u) acc = fmaf(hh[u], Wh2[u * (2 * M) + t], acc);
        out[b * (2 * M) + t] = acc;
    }
}

extern "C" void kernel_launch(void* const* d_in, const int* in_sizes, int n_in,
                              void* d_out, int out_size, void* d_ws, size_t ws_size,
                              hipStream_t stream)
{
    const float* points = (const float*)d_in[0];
    const float* Wm1 = (const float*)d_in[1];
    const float* bm1 = (const float*)d_in[2];
    const float* Wm2 = (const float*)d_in[3];
    const float* bm2 = (const float*)d_in[4];
    const float* Wc1 = (const float*)d_in[5];
    const float* bc1 = (const float*)d_in[6];
    const float* Wc2 = (const float*)d_in[7];
    const float* bc2 = (const float*)d_in[8];
    const float* Wr1 = (const float*)d_in[9];
    const float* br1 = (const float*)d_in[10];
    const float* Wr2 = (const float*)d_in[11];
    const float* br2 = (const float*)d_in[12];
    const float* Wf1 = (const float*)d_in[13];
    const float* bf1 = (const float*)d_in[14];
    const float* Wf2 = (const float*)d_in[15];
    const float* bf2 = (const float*)d_in[16];
    const float* Wh1 = (const float*)d_in[17];
    const float* bh1 = (const float*)d_in[18];
    const float* Wh2 = (const float*)d_in[19];
    const float* bh2 = (const float*)d_in[20];
    float* out = (float*)d_out;

    float* ws     = (float*)d_ws;
    float* metric = ws;                    // 32768
    float* mj     = ws + 32768;            // 262144
    float* S      = ws + 294912;           // 8192
    float* bc1s   = ws + 303104;           // 128
    float* Kc     = ws + 303232;           // 1
    int*   cnt    = (int*)(ws + 303236);   // 32 ints

    k_prep<<<B, 256, 0, stream>>>(points, Wm1, bm1, Wm2, bm2, Wr1, bc1, Wc2, bc2,
                                  metric, mj, S, bc1s, Kc, cnt);
    k_main<<<B * M, 512, 0, stream>>>(points, metric, mj, Wc1, Wc2, bc1s, Kc,
                                      Wr1, br1, S, cnt,
                                      Wr2, br2, Wf1, bf1, Wf2, bf2,
                                      Wh1, bh1, Wh2, bh2, out);
}

// Round 6
// 78.499 us; speedup vs baseline: 2.7387x; 1.1304x over previous
//
#include <hip/hip_runtime.h>

#define B 32
#define M 32
#define H 128
#define EPS 1e-6f
#define TSCALE 2.8853900817779268f   // 2*log2(e)

// ---------------- workspace layout (floats) ----------------
// metric @ 0      : 32768
// mj     @ 32768  : 262144   mj[b][j][d] = metric[b,j,:] @ Wr1[64:96]
// S      @ 294912 : 8192
// bc1s   @ 303104 : 128      bc1 * 2log2(e)
// Kc     @ 303232 : 1        sum(Wc2) + bc2
// cnt    @ 303236 : 32 ints
// Wp     @ 303268 : 262144   Wp[u][b][i] = sum_j sym(Wr2)[u,i,j] * p[b,j]
// c2     @ 565412 : 1024     c2[b][i]    = sum_j sym(br2)[i,j] * p[b,j]
// total ~2.27 MB

#define FMA4(P, s, W) \
    P.x = fmaf((s), (W).x, P.x); P.y = fmaf((s), (W).y, P.y); \
    P.z = fmaf((s), (W).z, P.z); P.w = fmaf((s), (W).w, P.w);

// Kernel 1, grid 289: blocks 0-31 = per-b prep (metric, mj, zero S/cnt,
// chris constants); blocks 32-287 = Wp row u = blk-32; block 288 = c2.
__global__ __launch_bounds__(256) void k_prep(
    const float* __restrict__ points, const float* __restrict__ Wm1,
    const float* __restrict__ bm1, const float* __restrict__ Wm2,
    const float* __restrict__ bm2, const float* __restrict__ Wr1,
    const float* __restrict__ bc1, const float* __restrict__ Wc2,
    const float* __restrict__ bc2, const float* __restrict__ Wr2,
    const float* __restrict__ br2,
    float* __restrict__ metric, float* __restrict__ mj,
    float* __restrict__ S, float* __restrict__ bc1s, float* __restrict__ Kc,
    int* __restrict__ cnt, float* __restrict__ Wp, float* __restrict__ c2)
{
    __shared__ float sbuf[3072];
    const int role = blockIdx.x, t = threadIdx.x;

    if (role >= B) {
        // ---- Wp / c2 path: symmetrize one Wr2 row, contract with points ----
        const int u = role - B;                 // 0..255 = Wr2 row, 256 = br2
        float* row    = sbuf;                   // 1024
        float* rowsym = sbuf + 1024;            // 1024
        float* ps     = sbuf + 2048;            // 1024 (all B*M points)
        const float* src = (u < 256) ? (Wr2 + u * 1024) : br2;
        #pragma unroll
        for (int r = 0; r < 4; ++r) {
            row[t + 256 * r] = src[t + 256 * r];
            ps[t + 256 * r]  = points[t + 256 * r];
        }
        __syncthreads();
        #pragma unroll
        for (int r = 0; r < 4; ++r) {
            const int d = t + 256 * r, ii = d >> 5, jj = d & 31;
            rowsym[d] = 0.5f * (row[d] + row[jj * 32 + ii]);
        }
        __syncthreads();
        const int b = t >> 3, i0 = (t & 7) * 4;
        const float4* rs4 = (const float4*)rowsym;
        const float4* p4  = (const float4*)(ps + b * 32);
        float4 o; o.x = o.y = o.z = o.w = 0.f;
        #pragma unroll
        for (int m = 0; m < 8; ++m) {
            const float4 pv = p4[m];
            const float4 r0 = rs4[(i0 + 0) * 8 + m];
            const float4 r1 = rs4[(i0 + 1) * 8 + m];
            const float4 r2 = rs4[(i0 + 2) * 8 + m];
            const float4 r3 = rs4[(i0 + 3) * 8 + m];
            o.x = fmaf(pv.x, r0.x, fmaf(pv.y, r0.y, fmaf(pv.z, r0.z, fmaf(pv.w, r0.w, o.x))));
            o.y = fmaf(pv.x, r1.x, fmaf(pv.y, r1.y, fmaf(pv.z, r1.z, fmaf(pv.w, r1.w, o.y))));
            o.z = fmaf(pv.x, r2.x, fmaf(pv.y, r2.y, fmaf(pv.z, r2.z, fmaf(pv.w, r2.w, o.z))));
            o.w = fmaf(pv.x, r3.x, fmaf(pv.y, r3.y, fmaf(pv.z, r3.z, fmaf(pv.w, r3.w, o.w))));
        }
        if (u < 256) ((float4*)(Wp + u * 1024 + b * 32))[t & 7] = o;
        else         ((float4*)(c2 + b * 32))[t & 7] = o;
        return;
    }

    // ---- per-b prep path ----
    const int b = role;
    float* p     = sbuf;           // 32
    float* h     = sbuf + 32;      // 128
    float* comps = sbuf + 160;     // 1024
    float* msym  = sbuf + 1184;    // 1024
    if (t < M) p[t] = points[b * M + t];
    __syncthreads();
    if (t < H) {
        float acc = bm1[t];
        #pragma unroll
        for (int m = 0; m < M; ++m) acc = fmaf(p[m], Wm1[m * H + t], acc);
        h[t] = fmaxf(acc, 0.f);
    }
    __syncthreads();
    #pragma unroll
    for (int r = 0; r < 4; ++r) {
        const int d = t + 256 * r;
        float acc = bm2[d];
        for (int u = 0; u < H; ++u) acc = fmaf(h[u], Wm2[u * (M * M) + d], acc);
        comps[d] = acc;
    }
    __syncthreads();
    #pragma unroll
    for (int r = 0; r < 4; ++r) {
        const int d = t + 256 * r;
        const int ii = d >> 5, jj = d & 31;
        float v = 0.5f * (comps[ii * M + jj] + comps[jj * M + ii]) + (ii == jj ? EPS : 0.f);
        metric[b * M * M + d] = v;
        msym[d] = v;
    }
    S[b * 256 + t] = 0.f;
    if (t == 0) cnt[b] = 0;
    __syncthreads();
    float wreg[M];
    #pragma unroll
    for (int m = 0; m < M; ++m) wreg[m] = Wr1[(64 + m) * 256 + t];
    const float4* msym4 = (const float4*)msym;
    for (int x = 0; x < M; ++x) {
        float acc = 0.f;
        #pragma unroll
        for (int mq = 0; mq < 8; ++mq) {
            float4 mv = msym4[x * 8 + mq];
            acc = fmaf(mv.x, wreg[4 * mq + 0], acc);
            acc = fmaf(mv.y, wreg[4 * mq + 1], acc);
            acc = fmaf(mv.z, wreg[4 * mq + 2], acc);
            acc = fmaf(mv.w, wreg[4 * mq + 3], acc);
        }
        mj[(b * M + x) * 256 + t] = acc;
    }
    if (b == 0) {
        if (t < H) bc1s[t] = bc1[t] * TSCALE;
        if (t == 0) {
            float s = bc2[0];
            for (int u = 0; u < H; ++u) s += Wc2[u];
            Kc[0] = s;
        }
    }
}

// Kernel 2: per block (b,i): christoffel MLP + ricci layer-1 + reduce into
// S[b]; the 32nd finishing block per b runs the (now tiny) epilogue using
// precomputed Wp/c2. 512 threads = 8 waves. LDS ~39 KB -> 4 blocks/CU.
// (512,6): (512,8) forced a 64-VGPR cap and spilled (round-4 regression).
__global__ __launch_bounds__(512, 6) void k_main(
    const float* __restrict__ points, const float* __restrict__ metric,
    const float* __restrict__ mj, const float* __restrict__ Wc1,
    const float* __restrict__ Wc2, const float* __restrict__ bc1s,
    const float* __restrict__ Kc, const float* __restrict__ Wr1,
    const float* __restrict__ br1, float* __restrict__ S,
    int* __restrict__ cnt,
    const float* __restrict__ Wp, const float* __restrict__ c2,
    const float* __restrict__ Wf1, const float* __restrict__ bf1,
    const float* __restrict__ Wf2, const float* __restrict__ bf2,
    const float* __restrict__ Wh1, const float* __restrict__ bh1,
    const float* __restrict__ Wh2, const float* __restrict__ bh2,
    float* __restrict__ out)
{
    const int blk = blockIdx.x;
    const int b = blk >> 5, i = blk & 31;
    const int t = threadIdx.x;

    __shared__ float wr1c[M * 256];   // Wr1[96:128] — 32 KB (epilogue scratch later)
    __shared__ float mc[M * M];       // metric[b] first, chris scratch after
    __shared__ float bmi[256];
    __shared__ float Slds[256];
    __shared__ int finflag;

    {
        const float4* src = (const float4*)(Wr1 + 96 * 256);
        float4* dst = (float4*)wr1c;
        #pragma unroll
        for (int r = 0; r < 4; ++r) dst[t + 512 * r] = src[t + 512 * r];
    }
    mc[t] = metric[b * 1024 + t];
    mc[t + 512] = metric[b * 1024 + t + 512];
    if (t < 256) Slds[t] = 0.f;
    __syncthreads();

    if (t < 256) {
        float acc = br1[t];
        #pragma unroll
        for (int m = 0; m < M; ++m) acc = fmaf(points[b * M + m], Wr1[m * 256 + t], acc);
        #pragma unroll
        for (int m = 0; m < M; ++m) acc = fmaf(mc[i * M + m], Wr1[(32 + m) * 256 + t], acc);
        bmi[t] = acc;
    }

    const int w = t >> 6, l = t & 63;
    const int ph = l >> 5, k = l & 31;
    const int j0 = 2 * w + ph, j1 = 16 + 2 * w + ph;
    const float gki  = mc[i * M + k] * TSCALE;   // metric symmetric
    const float gij0 = mc[i * M + j0] * TSCALE;
    const float gij1 = mc[i * M + j1] * TSCALE;
    const float gjk0 = mc[j0 * M + k] * TSCALE;
    const float gjk1 = mc[j1 * M + k] * TSCALE;
    __syncthreads();   // all mc(metric) reads done; bmi written

    // --- christoffel: both j's in one pass, shared gki term ---
    float acc_a = 0.f, acc_b = 0.f;
    #pragma unroll 8
    for (int u = 0; u < H; ++u) {
        float tc = fmaf(gki, Wc1[2 * H + u], bc1s[u]);
        float pa = fmaf(gij0, Wc1[u], fmaf(gjk0, Wc1[H + u], tc));
        float pb = fmaf(gij1, Wc1[u], fmaf(gjk1, Wc1[H + u], tc));
        acc_a = fmaf(__builtin_amdgcn_rcpf(__builtin_amdgcn_exp2f(pa) + 1.f), Wc2[u], acc_a);
        acc_b = fmaf(__builtin_amdgcn_rcpf(__builtin_amdgcn_exp2f(pb) + 1.f), Wc2[u], acc_b);
    }
    const float KcV = Kc[0];
    mc[w * 128 + l]      = fmaf(-2.f, acc_a, KcV);
    mc[w * 128 + 64 + l] = fmaf(-2.f, acc_b, KcV);
    __syncthreads();

    // --- ricci layer-1: lane l owns dims 4l..4l+3 for the wave's 4 j's ---
    const float4* mj4 = (const float4*)(mj + b * M * 256);
    const float4* wr1c4 = (const float4*)wr1c;
    const float* chw = mc + w * 128;
    float4 bmiv = ((const float4*)bmi)[l];
    const int jb = w * 2;
    float4 p00 = mj4[(jb + 0) * 64 + l];
    float4 p01 = mj4[(jb + 1) * 64 + l];
    float4 p10 = mj4[(jb + 16) * 64 + l];
    float4 p11 = mj4[(jb + 17) * 64 + l];
    p00.x += bmiv.x; p00.y += bmiv.y; p00.z += bmiv.z; p00.w += bmiv.w;
    p01.x += bmiv.x; p01.y += bmiv.y; p01.z += bmiv.z; p01.w += bmiv.w;
    p10.x += bmiv.x; p10.y += bmiv.y; p10.z += bmiv.z; p10.w += bmiv.w;
    p11.x += bmiv.x; p11.y += bmiv.y; p11.z += bmiv.z; p11.w += bmiv.w;

    #define STEP(W, kk) { \
        float s0 = chw[(kk)];      float s1 = chw[32 + (kk)]; \
        float s2 = chw[64 + (kk)]; float s3 = chw[96 + (kk)]; \
        FMA4(p00, s0, W); FMA4(p01, s1, W); FMA4(p10, s2, W); FMA4(p11, s3, W); }

    #pragma unroll
    for (int kc = 0; kc < 4; ++kc) {
        const int kb = kc * 8;
        float4 w0 = wr1c4[(kb + 0) * 64 + l];
        float4 w1 = wr1c4[(kb + 1) * 64 + l];
        float4 w2 = wr1c4[(kb + 2) * 64 + l];
        float4 w3 = wr1c4[(kb + 3) * 64 + l];
        float4 w4 = wr1c4[(kb + 4) * 64 + l];
        float4 w5 = wr1c4[(kb + 5) * 64 + l];
        float4 w6 = wr1c4[(kb + 6) * 64 + l];
        float4 w7 = wr1c4[(kb + 7) * 64 + l];
        STEP(w0, kb + 0) STEP(w1, kb + 1) STEP(w2, kb + 2) STEP(w3, kb + 3)
        STEP(w4, kb + 4) STEP(w5, kb + 5) STEP(w6, kb + 6) STEP(w7, kb + 7)
    }
    #undef STEP

    float r0 = fmaxf(p00.x,0.f)+fmaxf(p01.x,0.f)+fmaxf(p10.x,0.f)+fmaxf(p11.x,0.f);
    float r1 = fmaxf(p00.y,0.f)+fmaxf(p01.y,0.f)+fmaxf(p10.y,0.f)+fmaxf(p11.y,0.f);
    float r2 = fmaxf(p00.z,0.f)+fmaxf(p01.z,0.f)+fmaxf(p10.z,0.f)+fmaxf(p11.z,0.f);
    float r3 = fmaxf(p00.w,0.f)+fmaxf(p01.w,0.f)+fmaxf(p10.w,0.f)+fmaxf(p11.w,0.f);
    atomicAdd(&Slds[4*l + 0], r0);
    atomicAdd(&Slds[4*l + 1], r1);
    atomicAdd(&Slds[4*l + 2], r2);
    atomicAdd(&Slds[4*l + 3], r3);
    __syncthreads();
    if (t < 256) atomicAdd(&S[b * 256 + t], Slds[t]);
    asm volatile("s_waitcnt vmcnt(0)" ::: "memory");  // S atomics done before cnt
    __syncthreads();
    if (t == 0) {
        int old = atomicAdd(&cnt[b], 1);
        finflag = (old == 31);
    }
    __syncthreads();
    if (!finflag) return;

    // ===== tiny epilogue (one block per b): ricci_dir via Wp, then MLPs =====
    float* fs   = wr1c;          // 256
    float* rdp  = wr1c + 256;    // 512
    float* pl   = wr1c + 768;    // 32
    float* fin  = wr1c + 800;    // 64
    float* hf   = wr1c + 864;    // 128
    float* npos = wr1c + 992;    // 32
    float* hh   = wr1c + 1024;   // 128

    if (t < 256) fs[t] = atomicAdd(&S[b * 256 + t], 0.f) * (1.f / 1024.f);
    if (t < M) pl[t] = points[b * M + t];
    __syncthreads();
    {
        const int ii = t & 31, ch = t >> 5;   // 16 chunks x 16 u's
        float part = 0.f;
        #pragma unroll
        for (int uu = 0; uu < 16; ++uu) {
            const int u = ch * 16 + uu;
            part = fmaf(fs[u], Wp[u * 1024 + b * 32 + ii], part);
        }
        rdp[t] = part;
    }
    __syncthreads();
    if (t < M) {
        float a = c2[b * 32 + t];
        #pragma unroll
        for (int ch = 0; ch < 16; ++ch) a += rdp[ch * 32 + t];
        fin[t] = pl[t];
        fin[M + t] = a;
    }
    __syncthreads();
    if (t < H) {
        float acc = bf1[t];
        #pragma unroll
        for (int m = 0; m < 2 * M; ++m) acc = fmaf(fin[m], Wf1[m * H + t], acc);
        hf[t] = fmaxf(acc, 0.f);
    }
    __syncthreads();
    if (t < M) {
        float acc = bf2[t];
        #pragma unroll
        for (int u = 0; u < H; ++u) acc = fmaf(hf[u], Wf2[u * M + t], acc);
        npos[t] = pl[t] + acc;
    }
    __syncthreads();
    if (t < H) {
        float acc = bh1[t];
        #pragma unroll
        for (int m = 0; m < M; ++m) acc = fmaf(npos[m], Wh1[m * H + t], acc);
        hh[t] = tanhf(acc);
    }
    __syncthreads();
    if (t < 2 * M) {
        float acc = bh2[t];
        #pragma unroll
        for (int u = 0; u < H; ++u) acc = fmaf(hh[u], Wh2[u * (2 * M) + t], acc);
        out[b * (2 * M) + t] = acc;
    }
}

extern "C" void kernel_launch(void* const* d_in, const int* in_sizes, int n_in,
                              void* d_out, int out_size, void* d_ws, size_t ws_size,
                              hipStream_t stream)
{
    const float* points = (const float*)d_in[0];
    const float* Wm1 = (const float*)d_in[1];
    const float* bm1 = (const float*)d_in[2];
    const float* Wm2 = (const float*)d_in[3];
    const float* bm2 = (const float*)d_in[4];
    const float* Wc1 = (const float*)d_in[5];
    const float* bc1 = (const float*)d_in[6];
    const float* Wc2 = (const float*)d_in[7];
    const float* bc2 = (const float*)d_in[8];
    const float* Wr1 = (const float*)d_in[9];
    const float* br1 = (const float*)d_in[10];
    const float* Wr2 = (const float*)d_in[11];
    const float* br2 = (const float*)d_in[12];
    const float* Wf1 = (const float*)d_in[13];
    const float* bf1 = (const float*)d_in[14];
    const float* Wf2 = (const float*)d_in[15];
    const float* bf2 = (const float*)d_in[16];
    const float* Wh1 = (const float*)d_in[17];
    const float* bh1 = (const float*)d_in[18];
    const float* Wh2 = (const float*)d_in[19];
    const float* bh2 = (const float*)d_in[20];
    float* out = (float*)d_out;

    float* ws     = (float*)d_ws;
    float* metric = ws;                    // 32768
    float* mj     = ws + 32768;            // 262144
    float* S      = ws + 294912;           // 8192
    float* bc1s   = ws + 303104;           // 128
    float* Kc     = ws + 303232;           // 1
    int*   cnt    = (int*)(ws + 303236);   // 32 ints
    float* Wp     = ws + 303268;           // 262144
    float* c2     = ws + 565412;           // 1024

    k_prep<<<289, 256, 0, stream>>>(points, Wm1, bm1, Wm2, bm2, Wr1, bc1, Wc2,
                                    bc2, Wr2, br2, metric, mj, S, bc1s, Kc,
                                    cnt, Wp, c2);
    k_main<<<B * M, 512, 0, stream>>>(points, metric, mj, Wc1, Wc2, bc1s, Kc,
                                      Wr1, br1, S, cnt,
                                      Wp, c2, Wf1, bf1, Wf2, bf2,
                                      Wh1, bh1, Wh2, bh2, out);
}

// Round 7
// 78.442 us; speedup vs baseline: 2.7407x; 1.0007x over previous
//
#include <hip/hip_runtime.h>

#define B 32
#define M 32
#define H 128
#define EPS 1e-6f
#define TSCALE 2.8853900817779268f   // 2*log2(e)

// ---------------- workspace layout (floats) ----------------
// metric @ 0      : 32768
// mj     @ 32768  : 262144   mj[b][j][d] = metric[b,j,:] @ Wr1[64:96]
// S      @ 294912 : 8192
// bc1s   @ 303104 : 128      bc1 * 2log2(e)
// Kc     @ 303232 : 1        sum(Wc2) + bc2
// cnt    @ 303236 : 32 ints
// Wp     @ 303268 : 262144   Wp[u][b][i] = sum_j sym(Wr2)[u,i,j] * p[b,j]
// c2     @ 565412 : 1024     c2[b][i]    = sum_j sym(br2)[i,j] * p[b,j]
// total ~2.27 MB

#define FMA4(P, s, W) \
    P.x = fmaf((s), (W).x, P.x); P.y = fmaf((s), (W).y, P.y); \
    P.z = fmaf((s), (W).z, P.z); P.w = fmaf((s), (W).w, P.w);

// Kernel 1, grid 289: blocks 0-31 = per-b prep (metric, mj, zero S/cnt,
// chris constants); blocks 32-287 = Wp row u = blk-32; block 288 = c2.
__global__ __launch_bounds__(256) void k_prep(
    const float* __restrict__ points, const float* __restrict__ Wm1,
    const float* __restrict__ bm1, const float* __restrict__ Wm2,
    const float* __restrict__ bm2, const float* __restrict__ Wr1,
    const float* __restrict__ bc1, const float* __restrict__ Wc2,
    const float* __restrict__ bc2, const float* __restrict__ Wr2,
    const float* __restrict__ br2,
    float* __restrict__ metric, float* __restrict__ mj,
    float* __restrict__ S, float* __restrict__ bc1s, float* __restrict__ Kc,
    int* __restrict__ cnt, float* __restrict__ Wp, float* __restrict__ c2)
{
    __shared__ float sbuf[3072];
    const int role = blockIdx.x, t = threadIdx.x;

    if (role >= B) {
        // ---- Wp / c2 path: symmetrize one Wr2 row, contract with points ----
        const int u = role - B;                 // 0..255 = Wr2 row, 256 = br2
        float* row    = sbuf;                   // 1024
        float* rowsym = sbuf + 1024;            // 1024
        float* ps     = sbuf + 2048;            // 1024 (all B*M points)
        const float* src = (u < 256) ? (Wr2 + u * 1024) : br2;
        #pragma unroll
        for (int r = 0; r < 4; ++r) {
            row[t + 256 * r] = src[t + 256 * r];
            ps[t + 256 * r]  = points[t + 256 * r];
        }
        __syncthreads();
        #pragma unroll
        for (int r = 0; r < 4; ++r) {
            const int d = t + 256 * r, ii = d >> 5, jj = d & 31;
            rowsym[d] = 0.5f * (row[d] + row[jj * 32 + ii]);
        }
        __syncthreads();
        const int b = t >> 3, i0 = (t & 7) * 4;
        const float4* rs4 = (const float4*)rowsym;
        const float4* p4  = (const float4*)(ps + b * 32);
        float4 o; o.x = o.y = o.z = o.w = 0.f;
        #pragma unroll
        for (int m = 0; m < 8; ++m) {
            const float4 pv = p4[m];
            const float4 r0 = rs4[(i0 + 0) * 8 + m];
            const float4 r1 = rs4[(i0 + 1) * 8 + m];
            const float4 r2 = rs4[(i0 + 2) * 8 + m];
            const float4 r3 = rs4[(i0 + 3) * 8 + m];
            o.x = fmaf(pv.x, r0.x, fmaf(pv.y, r0.y, fmaf(pv.z, r0.z, fmaf(pv.w, r0.w, o.x))));
            o.y = fmaf(pv.x, r1.x, fmaf(pv.y, r1.y, fmaf(pv.z, r1.z, fmaf(pv.w, r1.w, o.y))));
            o.z = fmaf(pv.x, r2.x, fmaf(pv.y, r2.y, fmaf(pv.z, r2.z, fmaf(pv.w, r2.w, o.z))));
            o.w = fmaf(pv.x, r3.x, fmaf(pv.y, r3.y, fmaf(pv.z, r3.z, fmaf(pv.w, r3.w, o.w))));
        }
        if (u < 256) ((float4*)(Wp + u * 1024 + b * 32))[t & 7] = o;
        else         ((float4*)(c2 + b * 32))[t & 7] = o;
        return;
    }

    // ---- per-b prep path ----
    const int b = role;
    float* p     = sbuf;           // 32
    float* h     = sbuf + 32;      // 128
    float* comps = sbuf + 160;     // 1024
    float* msym  = sbuf + 1184;    // 1024
    if (t < M) p[t] = points[b * M + t];
    __syncthreads();
    if (t < H) {
        float acc = bm1[t];
        #pragma unroll
        for (int m = 0; m < M; ++m) acc = fmaf(p[m], Wm1[m * H + t], acc);
        h[t] = fmaxf(acc, 0.f);
    }
    __syncthreads();
    #pragma unroll
    for (int r = 0; r < 4; ++r) {
        const int d = t + 256 * r;
        float acc = bm2[d];
        for (int u = 0; u < H; ++u) acc = fmaf(h[u], Wm2[u * (M * M) + d], acc);
        comps[d] = acc;
    }
    __syncthreads();
    #pragma unroll
    for (int r = 0; r < 4; ++r) {
        const int d = t + 256 * r;
        const int ii = d >> 5, jj = d & 31;
        float v = 0.5f * (comps[ii * M + jj] + comps[jj * M + ii]) + (ii == jj ? EPS : 0.f);
        metric[b * M * M + d] = v;
        msym[d] = v;
    }
    S[b * 256 + t] = 0.f;
    if (t == 0) cnt[b] = 0;
    __syncthreads();
    float wreg[M];
    #pragma unroll
    for (int m = 0; m < M; ++m) wreg[m] = Wr1[(64 + m) * 256 + t];
    const float4* msym4 = (const float4*)msym;
    for (int x = 0; x < M; ++x) {
        float acc = 0.f;
        #pragma unroll
        for (int mq = 0; mq < 8; ++mq) {
            float4 mv = msym4[x * 8 + mq];
            acc = fmaf(mv.x, wreg[4 * mq + 0], acc);
            acc = fmaf(mv.y, wreg[4 * mq + 1], acc);
            acc = fmaf(mv.z, wreg[4 * mq + 2], acc);
            acc = fmaf(mv.w, wreg[4 * mq + 3], acc);
        }
        mj[(b * M + x) * 256 + t] = acc;
    }
    if (b == 0) {
        if (t < H) bc1s[t] = bc1[t] * TSCALE;
        if (t == 0) {
            float s = bc2[0];
            for (int u = 0; u < H; ++u) s += Wc2[u];
            Kc[0] = s;
        }
    }
}

// Kernel 2: per block (b,i): christoffel MLP + ricci layer-1 + reduce into
// S[b]; the 32nd finishing block per b runs the (now tiny) epilogue using
// precomputed Wp/c2. 512 threads = 8 waves. LDS ~39 KB -> 4 blocks/CU.
// (512,6): (512,8) forced a 64-VGPR cap and spilled (round-4 regression).
__global__ __launch_bounds__(512, 6) void k_main(
    const float* __restrict__ points, const float* __restrict__ metric,
    const float* __restrict__ mj, const float* __restrict__ Wc1,
    const float* __restrict__ Wc2, const float* __restrict__ bc1s,
    const float* __restrict__ Kc, const float* __restrict__ Wr1,
    const float* __restrict__ br1, float* __restrict__ S,
    int* __restrict__ cnt,
    const float* __restrict__ Wp, const float* __restrict__ c2,
    const float* __restrict__ Wf1, const float* __restrict__ bf1,
    const float* __restrict__ Wf2, const float* __restrict__ bf2,
    const float* __restrict__ Wh1, const float* __restrict__ bh1,
    const float* __restrict__ Wh2, const float* __restrict__ bh2,
    float* __restrict__ out)
{
    const int blk = blockIdx.x;
    const int b = blk >> 5, i = blk & 31;
    const int t = threadIdx.x;

    __shared__ float wr1c[M * 256];   // Wr1[96:128] — 32 KB (epilogue scratch later)
    __shared__ float mc[M * M];       // metric[b] first, chris scratch after
    __shared__ float bmi[256];
    __shared__ float Slds[256];
    __shared__ int finflag;

    {
        const float4* src = (const float4*)(Wr1 + 96 * 256);
        float4* dst = (float4*)wr1c;
        #pragma unroll
        for (int r = 0; r < 4; ++r) dst[t + 512 * r] = src[t + 512 * r];
    }
    mc[t] = metric[b * 1024 + t];
    mc[t + 512] = metric[b * 1024 + t + 512];
    if (t < 256) Slds[t] = 0.f;
    __syncthreads();

    if (t < 256) {
        float acc = br1[t];
        #pragma unroll
        for (int m = 0; m < M; ++m) acc = fmaf(points[b * M + m], Wr1[m * 256 + t], acc);
        #pragma unroll
        for (int m = 0; m < M; ++m) acc = fmaf(mc[i * M + m], Wr1[(32 + m) * 256 + t], acc);
        bmi[t] = acc;
    }

    const int w = t >> 6, l = t & 63;
    const int ph = l >> 5, k = l & 31;
    const int j0 = 2 * w + ph, j1 = 16 + 2 * w + ph;
    const float gki  = mc[i * M + k] * TSCALE;   // metric symmetric
    const float gij0 = mc[i * M + j0] * TSCALE;
    const float gij1 = mc[i * M + j1] * TSCALE;
    const float gjk0 = mc[j0 * M + k] * TSCALE;
    const float gjk1 = mc[j1 * M + k] * TSCALE;
    __syncthreads();   // all mc(metric) reads done; bmi written

    // --- christoffel: both j's in one pass, shared gki term ---
    float acc_a = 0.f, acc_b = 0.f;
    #pragma unroll 8
    for (int u = 0; u < H; ++u) {
        float tc = fmaf(gki, Wc1[2 * H + u], bc1s[u]);
        float pa = fmaf(gij0, Wc1[u], fmaf(gjk0, Wc1[H + u], tc));
        float pb = fmaf(gij1, Wc1[u], fmaf(gjk1, Wc1[H + u], tc));
        acc_a = fmaf(__builtin_amdgcn_rcpf(__builtin_amdgcn_exp2f(pa) + 1.f), Wc2[u], acc_a);
        acc_b = fmaf(__builtin_amdgcn_rcpf(__builtin_amdgcn_exp2f(pb) + 1.f), Wc2[u], acc_b);
    }
    const float KcV = Kc[0];
    mc[w * 128 + l]      = fmaf(-2.f, acc_a, KcV);
    mc[w * 128 + 64 + l] = fmaf(-2.f, acc_b, KcV);
    __syncthreads();

    // --- ricci layer-1: lane l owns dims 4l..4l+3 for the wave's 4 j's ---
    const float4* mj4 = (const float4*)(mj + b * M * 256);
    const float4* wr1c4 = (const float4*)wr1c;
    const float* chw = mc + w * 128;
    float4 bmiv = ((const float4*)bmi)[l];
    const int jb = w * 2;
    float4 p00 = mj4[(jb + 0) * 64 + l];
    float4 p01 = mj4[(jb + 1) * 64 + l];
    float4 p10 = mj4[(jb + 16) * 64 + l];
    float4 p11 = mj4[(jb + 17) * 64 + l];
    p00.x += bmiv.x; p00.y += bmiv.y; p00.z += bmiv.z; p00.w += bmiv.w;
    p01.x += bmiv.x; p01.y += bmiv.y; p01.z += bmiv.z; p01.w += bmiv.w;
    p10.x += bmiv.x; p10.y += bmiv.y; p10.z += bmiv.z; p10.w += bmiv.w;
    p11.x += bmiv.x; p11.y += bmiv.y; p11.z += bmiv.z; p11.w += bmiv.w;

    #define STEP(W, kk) { \
        float s0 = chw[(kk)];      float s1 = chw[32 + (kk)]; \
        float s2 = chw[64 + (kk)]; float s3 = chw[96 + (kk)]; \
        FMA4(p00, s0, W); FMA4(p01, s1, W); FMA4(p10, s2, W); FMA4(p11, s3, W); }

    #pragma unroll
    for (int kc = 0; kc < 4; ++kc) {
        const int kb = kc * 8;
        float4 w0 = wr1c4[(kb + 0) * 64 + l];
        float4 w1 = wr1c4[(kb + 1) * 64 + l];
        float4 w2 = wr1c4[(kb + 2) * 64 + l];
        float4 w3 = wr1c4[(kb + 3) * 64 + l];
        float4 w4 = wr1c4[(kb + 4) * 64 + l];
        float4 w5 = wr1c4[(kb + 5) * 64 + l];
        float4 w6 = wr1c4[(kb + 6) * 64 + l];
        float4 w7 = wr1c4[(kb + 7) * 64 + l];
        STEP(w0, kb + 0) STEP(w1, kb + 1) STEP(w2, kb + 2) STEP(w3, kb + 3)
        STEP(w4, kb + 4) STEP(w5, kb + 5) STEP(w6, kb + 6) STEP(w7, kb + 7)
    }
    #undef STEP

    float r0 = fmaxf(p00.x,0.f)+fmaxf(p01.x,0.f)+fmaxf(p10.x,0.f)+fmaxf(p11.x,0.f);
    float r1 = fmaxf(p00.y,0.f)+fmaxf(p01.y,0.f)+fmaxf(p10.y,0.f)+fmaxf(p11.y,0.f);
    float r2 = fmaxf(p00.z,0.f)+fmaxf(p01.z,0.f)+fmaxf(p10.z,0.f)+fmaxf(p11.z,0.f);
    float r3 = fmaxf(p00.w,0.f)+fmaxf(p01.w,0.f)+fmaxf(p10.w,0.f)+fmaxf(p11.w,0.f);
    atomicAdd(&Slds[4*l + 0], r0);
    atomicAdd(&Slds[4*l + 1], r1);
    atomicAdd(&Slds[4*l + 2], r2);
    atomicAdd(&Slds[4*l + 3], r3);
    __syncthreads();
    if (t < 256) atomicAdd(&S[b * 256 + t], Slds[t]);
    asm volatile("s_waitcnt vmcnt(0)" ::: "memory");  // S atomics done before cnt
    __syncthreads();
    if (t == 0) {
        int old = atomicAdd(&cnt[b], 1);
        finflag = (old == 31);
    }
    __syncthreads();
    if (!finflag) return;

    // ===== tiny epilogue (one block per b): ricci_dir via Wp, then MLPs =====
    float* fs   = wr1c;          // 256
    float* rdp  = wr1c + 256;    // 512
    float* pl   = wr1c + 768;    // 32
    float* fin  = wr1c + 800;    // 64
    float* hf   = wr1c + 864;    // 128
    float* npos = wr1c + 992;    // 32
    float* hh   = wr1c + 1024;   // 128

    if (t < 256) fs[t] = atomicAdd(&S[b * 256 + t], 0.f) * (1.f / 1024.f);
    if (t < M) pl[t] = points[b * M + t];
    __syncthreads();
    {
        const int ii = t & 31, ch = t >> 5;   // 16 chunks x 16 u's
        float part = 0.f;
        #pragma unroll
        for (int uu = 0; uu < 16; ++uu) {
            const int u = ch * 16 + uu;
            part = fmaf(fs[u], Wp[u * 1024 + b * 32 + ii], part);
        }
        rdp[t] = part;
    }
    __syncthreads();
    if (t < M) {
        float a = c2[b * 32 + t];
        #pragma unroll
        for (int ch = 0; ch < 16; ++ch) a += rdp[ch * 32 + t];
        fin[t] = pl[t];
        fin[M + t] = a;
    }
    __syncthreads();
    if (t < H) {
        float acc = bf1[t];
        #pragma unroll
        for (int m = 0; m < 2 * M; ++m) acc = fmaf(fin[m], Wf1[m * H + t], acc);
        hf[t] = fmaxf(acc, 0.f);
    }
    __syncthreads();
    if (t < M) {
        float acc = bf2[t];
        #pragma unroll
        for (int u = 0; u < H; ++u) acc = fmaf(hf[u], Wf2[u * M + t], acc);
        npos[t] = pl[t] + acc;
    }
    __syncthreads();
    if (t < H) {
        float acc = bh1[t];
        #pragma unroll
        for (int m = 0; m < M; ++m) acc = fmaf(npos[m], Wh1[m * H + t], acc);
        hh[t] = tanhf(acc);
    }
    __syncthreads();
    if (t < 2 * M) {
        float acc = bh2[t];
        #pragma unroll
        for (int u = 0; u < H; ++u) acc = fmaf(hh[u], Wh2[u * (2 * M) + t], acc);
        out[b * (2 * M) + t] = acc;
    }
}

extern "C" void kernel_launch(void* const* d_in, const int* in_sizes, int n_in,
                              void* d_out, int out_size, void* d_ws, size_t ws_size,
                              hipStream_t stream)
{
    const float* points = (const float*)d_in[0];
    const float* Wm1 = (const float*)d_in[1];
    const float* bm1 = (const float*)d_in[2];
    const float* Wm2 = (const float*)d_in[3];
    const float* bm2 = (const float*)d_in[4];
    const float* Wc1 = (const float*)d_in[5];
    const float* bc1 = (const float*)d_in[6];
    const float* Wc2 = (const float*)d_in[7];
    const float* bc2 = (const float*)d_in[8];
    const float* Wr1 = (const float*)d_in[9];
    const float* br1 = (const float*)d_in[10];
    const float* Wr2 = (const float*)d_in[11];
    const float* br2 = (const float*)d_in[12];
    const float* Wf1 = (const float*)d_in[13];
    const float* bf1 = (const float*)d_in[14];
    const float* Wf2 = (const float*)d_in[15];
    const float* bf2 = (const float*)d_in[16];
    const float* Wh1 = (const float*)d_in[17];
    const float* bh1 = (const float*)d_in[18];
    const float* Wh2 = (const float*)d_in[19];
    const float* bh2 = (const float*)d_in[20];
    float* out = (float*)d_out;

    float* ws     = (float*)d_ws;
    float* metric = ws;                    // 32768
    float* mj     = ws + 32768;            // 262144
    float* S      = ws + 294912;           // 8192
    float* bc1s   = ws + 303104;           // 128
    float* Kc     = ws + 303232;           // 1
    int*   cnt    = (int*)(ws + 303236);   // 32 ints
    float* Wp     = ws + 303268;           // 262144
    float* c2     = ws + 565412;           // 1024

    k_prep<<<289, 256, 0, stream>>>(points, Wm1, bm1, Wm2, bm2, Wr1, bc1, Wc2,
                                    bc2, Wr2, br2, metric, mj, S, bc1s, Kc,
                                    cnt, Wp, c2);
    k_main<<<B * M, 512, 0, stream>>>(points, metric, mj, Wc1, Wc2, bc1s, Kc,
                                      Wr1, br1, S, cnt,
                                      Wp, c2, Wf1, bf1, Wf2, bf2,
                                      Wh1, bh1, Wh2, bh2, out);
}